// Round 6
// baseline (803.120 us; speedup 1.0000x reference)
//
#include <hip/hip_runtime.h>
#include <hip/hip_bf16.h>
#include <math.h>

namespace {

constexpr int kB = 32;
constexpr int kS = 2048;
constexpr int kI = 32;
constexpr int kW = 20;
constexpr int kH = 128;
constexpr int kNwin = kS - kW + 1;   // 2029
constexpr int kT = kS - 2 * kW;      // 2008
constexpr float kEps = 1e-5f;

typedef __attribute__((ext_vector_type(8))) short short8;          // 8 bf16 (4 VGPR)
typedef __attribute__((ext_vector_type(8))) unsigned short ush8;   // 16B copy unit
typedef __attribute__((ext_vector_type(4))) float f32x4;

__device__ __forceinline__ unsigned short f2bf(float f) {          // RNE f32->bf16
    unsigned u = __builtin_bit_cast(unsigned, f);
    u += 0x7FFFu + ((u >> 16) & 1u);
    return (unsigned short)(u >> 16);
}
__device__ __forceinline__ float bf2f(unsigned short h) {
    unsigned u = ((unsigned)h) << 16;
    return __builtin_bit_cast(float, u);
}
__device__ __forceinline__ float gelu_exact(float v) {
    return 0.5f * v * (1.0f + erff(v * 0.70710678118654752440f));
}

// ---- workspace layout (bytes) ----
constexpr size_t ENC_OFF = 0;                       // 32*2048*128 bf16 = 16 MB
constexpr size_t XBF_OFF = 16777216;                // 32*2048*32 bf16 = 4 MB
constexpr size_t WET_OFF = XBF_OFF + 4194304;       // WencT [128][640] bf16
constexpr size_t W1T_OFF = WET_OFF + 163840;        // W1T [128][256] bf16
constexpr size_t W2T_OFF = W1T_OFF + 65536;         // W2T [64][128] bf16
constexpr size_t FC_OFF  = W2T_OFF + 16384;         // flag counter (16B)
constexpr size_t FL_OFF  = FC_OFF + 16;             // flag list (64256 u32)

// ================= prep: bf16 conversions + W transposes =================
__global__ void prep_kernel(const float* __restrict__ x, const float* __restrict__ Wenc,
                            const float* __restrict__ W1, const float* __restrict__ W2,
                            unsigned short* __restrict__ xbf, unsigned short* __restrict__ WencT,
                            unsigned short* __restrict__ W1T, unsigned short* __restrict__ W2T)
{
    const int tid = blockIdx.x * blockDim.x + threadIdx.x;
    const int nth = gridDim.x * blockDim.x;
    for (int i = tid; i < (kB * kS * kI) / 4; i += nth) {
        float4 v = reinterpret_cast<const float4*>(x)[i];
        unsigned short o[4] = {f2bf(v.x), f2bf(v.y), f2bf(v.z), f2bf(v.w)};
        *reinterpret_cast<uint2*>(xbf + i * 4) = *reinterpret_cast<uint2*>(o);
    }
    for (int i = tid; i < kH * 640; i += nth) {     // WencT[n][k] = Wenc[k][n]
        int n = i / 640, k = i - n * 640;
        WencT[i] = f2bf(Wenc[(size_t)k * kH + n]);
    }
    for (int i = tid; i < kH * 256; i += nth) {     // W1T[n][k]
        int n = i >> 8, k = i & 255;
        W1T[i] = f2bf(W1[(size_t)k * kH + n]);
    }
    for (int i = tid; i < 64 * kH; i += nth) {      // W2T[n][k]
        int n = i >> 7, k = i & 127;
        W2T[i] = f2bf(W2[(size_t)k * 64 + n]);
    }
}

// ================= encoder: MFMA GEMM + LN + GELU =================
// Block: 128 t-rows x 128 cols, 256 thr = 4 waves; wave w: rows w*32..+31
// (2 m-frags), 8 n-frags; K=640 in 20 steps of 32.
constexpr int AP = 40;    // LDS pitch in ushorts (80B): 16B-aligned, ~2-way banks

__global__ __launch_bounds__(256, 2)
void enc_kernel(const unsigned short* __restrict__ xbf, const unsigned short* __restrict__ WencT,
                const float* __restrict__ benc, const float* __restrict__ gma,
                const float* __restrict__ bta, unsigned short* __restrict__ encb)
{
    __shared__ unsigned short xs[148 * AP];   // x rows t0..t0+147, 32 bf16 each
    __shared__ unsigned short wt[128 * AP];   // WencT tile [n=128][32]
    __shared__ float prm[384];                // benc | gamma | beta

    const int tid = threadIdx.x, b = blockIdx.y, t0 = blockIdx.x * 128;
    const int l = tid & 63, w = tid >> 6;
    const int cb = l & 15, rg = l >> 4;

    if (tid < 128) { prm[tid] = benc[tid]; prm[128 + tid] = gma[tid]; prm[256 + tid] = bta[tid]; }

    for (int i = tid; i < 148 * 4; i += 256) {     // stage x (bf16) rows
        int r = i >> 2, q = i & 3;
        int gr = t0 + r; if (gr > kS - 1) gr = kS - 1;
        ush8 v = *reinterpret_cast<const ush8*>(xbf + ((size_t)(b * kS + gr)) * kI + q * 8);
        *reinterpret_cast<ush8*>(&xs[r * AP + q * 8]) = v;
    }

    f32x4 acc[2][8];
    #pragma unroll
    for (int mi = 0; mi < 2; ++mi)
        #pragma unroll
        for (int nf = 0; nf < 8; ++nf) acc[mi][nf] = f32x4{0.f, 0.f, 0.f, 0.f};

    for (int kc = 0; kc < 20; ++kc) {
        __syncthreads();
        for (int i = tid; i < 128 * 4; i += 256) { // stage W tile
            int n = i >> 2, q = i & 3;
            ush8 v = *reinterpret_cast<const ush8*>(WencT + (size_t)n * 640 + kc * 32 + q * 8);
            *reinterpret_cast<ush8*>(&wt[n * AP + q * 8]) = v;
        }
        __syncthreads();
        // A[t][kk] = x[t+kc][kk]; lane: m = cb, k = rg*8+j
        short8 a0 = *reinterpret_cast<const short8*>(&xs[(w * 32 + cb + kc) * AP + rg * 8]);
        short8 a1 = *reinterpret_cast<const short8*>(&xs[(w * 32 + 16 + cb + kc) * AP + rg * 8]);
        #pragma unroll
        for (int nf = 0; nf < 8; ++nf) {
            short8 bf = *reinterpret_cast<const short8*>(&wt[(nf * 16 + cb) * AP + rg * 8]);
            acc[0][nf] = __builtin_amdgcn_mfma_f32_16x16x32_bf16(a0, bf, acc[0][nf], 0, 0, 0);
            acc[1][nf] = __builtin_amdgcn_mfma_f32_16x16x32_bf16(a1, bf, acc[1][nf], 0, 0, 0);
        }
    }

    // epilogue: C/D layout col = lane&15, row = (lane>>4)*4 + reg
    #pragma unroll
    for (int mi = 0; mi < 2; ++mi) {
        #pragma unroll
        for (int r = 0; r < 4; ++r) {
            const int rl = w * 32 + mi * 16 + rg * 4 + r;
            const int t = t0 + rl;
            float h[8];
            float s = 0.f;
            #pragma unroll
            for (int nf = 0; nf < 8; ++nf) { h[nf] = acc[mi][nf][r] + prm[nf * 16 + cb]; s += h[nf]; }
            s += __shfl_xor(s, 1); s += __shfl_xor(s, 2); s += __shfl_xor(s, 4); s += __shfl_xor(s, 8);
            const float mu = s * (1.f / 128.f);
            float s2 = 0.f;
            #pragma unroll
            for (int nf = 0; nf < 8; ++nf) { h[nf] -= mu; s2 += h[nf] * h[nf]; }
            s2 += __shfl_xor(s2, 1); s2 += __shfl_xor(s2, 2); s2 += __shfl_xor(s2, 4); s2 += __shfl_xor(s2, 8);
            const float rstd = 1.f / sqrtf(s2 * (1.f / 128.f) + kEps);
            if (t < kNwin) {
                unsigned short* dst = encb + ((size_t)(b * kS + t)) * kH;
                #pragma unroll
                for (int nf = 0; nf < 8; ++nf) {
                    float v = gelu_exact(h[nf] * rstd * prm[128 + nf * 16 + cb] + prm[256 + nf * 16 + cb]);
                    dst[nf * 16 + cb] = f2bf(v);
                }
            }
        }
    }
}

// ================= comparator: MFMA layers 1-2, vector layer 3 =================
constexpr int EP = 136;   // ebuf/z1 pitch ushorts (272B)
constexpr int ZP = 72;    // z2 pitch ushorts (144B)

__global__ __launch_bounds__(256, 2)
void cmp_kernel(const unsigned short* __restrict__ encb, const unsigned short* __restrict__ W1T,
                const float* __restrict__ b1, const unsigned short* __restrict__ W2T,
                const float* __restrict__ b2, const float* __restrict__ W3,
                const float* __restrict__ b3, float* __restrict__ out,
                int* __restrict__ fcnt, unsigned int* __restrict__ flist)
{
    __shared__ unsigned short pool[26624];  // ebuf 148x136 | later z1 128x136 + z2 128x72
    __shared__ unsigned short wt[128 * AP];
    __shared__ float prm[192];              // b1 | b2

    unsigned short* ebuf = pool;
    unsigned short* z1   = pool;
    unsigned short* z2   = pool + 17408;

    const int tid = threadIdx.x, b = blockIdx.y, t0 = blockIdx.x * 128;
    const int l = tid & 63, w = tid >> 6;
    const int cb = l & 15, rg = l >> 4;

    if (tid < 128) prm[tid] = b1[tid];
    else if (tid < 192) prm[tid] = b2[tid - 128];   // prm[128..191] = b2[0..63]  (R5 bug fixed)

    for (int i = tid; i < 148 * 16; i += 256) {          // stage enc rows t0..t0+147
        int r = i >> 4, q = i & 15;
        int gr = t0 + r; if (gr > kNwin - 1) gr = kNwin - 1;
        ush8 v = *reinterpret_cast<const ush8*>(encb + ((size_t)(b * kS + gr)) * kH + q * 8);
        *reinterpret_cast<ush8*>(&ebuf[r * EP + q * 8]) = v;
    }

    // ---- layer 1: A[t][k] = enc[t + (k<128?0:20)][k&127], K=256, N=128
    f32x4 acc1[2][8];
    #pragma unroll
    for (int mi = 0; mi < 2; ++mi)
        #pragma unroll
        for (int nf = 0; nf < 8; ++nf) acc1[mi][nf] = f32x4{0.f, 0.f, 0.f, 0.f};

    for (int kc = 0; kc < 8; ++kc) {
        __syncthreads();
        for (int i = tid; i < 128 * 4; i += 256) {
            int n = i >> 2, q = i & 3;
            ush8 v = *reinterpret_cast<const ush8*>(W1T + (size_t)n * 256 + kc * 32 + q * 8);
            *reinterpret_cast<ush8*>(&wt[n * AP + q * 8]) = v;
        }
        __syncthreads();
        const int ro = (kc >= 4) ? kW : 0, co = (kc & 3) * 32;
        short8 a0 = *reinterpret_cast<const short8*>(&ebuf[(ro + w * 32 + cb) * EP + co + rg * 8]);
        short8 a1 = *reinterpret_cast<const short8*>(&ebuf[(ro + w * 32 + 16 + cb) * EP + co + rg * 8]);
        #pragma unroll
        for (int nf = 0; nf < 8; ++nf) {
            short8 bf = *reinterpret_cast<const short8*>(&wt[(nf * 16 + cb) * AP + rg * 8]);
            acc1[0][nf] = __builtin_amdgcn_mfma_f32_16x16x32_bf16(a0, bf, acc1[0][nf], 0, 0, 0);
            acc1[1][nf] = __builtin_amdgcn_mfma_f32_16x16x32_bf16(a1, bf, acc1[1][nf], 0, 0, 0);
        }
    }
    __syncthreads();    // all ebuf reads done; z1 overlays it
    #pragma unroll
    for (int mi = 0; mi < 2; ++mi)
        #pragma unroll
        for (int r = 0; r < 4; ++r) {
            const int rl = w * 32 + mi * 16 + rg * 4 + r;
            #pragma unroll
            for (int nf = 0; nf < 8; ++nf)
                z1[rl * EP + nf * 16 + cb] = f2bf(gelu_exact(acc1[mi][nf][r] + prm[nf * 16 + cb]));
        }

    // ---- layer 2: K=128, N=64
    f32x4 acc2[2][4];
    #pragma unroll
    for (int mi = 0; mi < 2; ++mi)
        #pragma unroll
        for (int nf = 0; nf < 4; ++nf) acc2[mi][nf] = f32x4{0.f, 0.f, 0.f, 0.f};

    for (int kc = 0; kc < 4; ++kc) {
        __syncthreads();
        {   // stage W2T tile: 64 rows x 32 k
            int n = tid >> 2, q = tid & 3;
            if (n < 64) {
                ush8 v = *reinterpret_cast<const ush8*>(W2T + (size_t)n * 128 + kc * 32 + q * 8);
                *reinterpret_cast<ush8*>(&wt[n * AP + q * 8]) = v;
            }
        }
        __syncthreads();
        short8 a0 = *reinterpret_cast<const short8*>(&z1[(w * 32 + cb) * EP + kc * 32 + rg * 8]);
        short8 a1 = *reinterpret_cast<const short8*>(&z1[(w * 32 + 16 + cb) * EP + kc * 32 + rg * 8]);
        #pragma unroll
        for (int nf = 0; nf < 4; ++nf) {
            short8 bf = *reinterpret_cast<const short8*>(&wt[(nf * 16 + cb) * AP + rg * 8]);
            acc2[0][nf] = __builtin_amdgcn_mfma_f32_16x16x32_bf16(a0, bf, acc2[0][nf], 0, 0, 0);
            acc2[1][nf] = __builtin_amdgcn_mfma_f32_16x16x32_bf16(a1, bf, acc2[1][nf], 0, 0, 0);
        }
    }
    __syncthreads();
    #pragma unroll
    for (int mi = 0; mi < 2; ++mi)
        #pragma unroll
        for (int r = 0; r < 4; ++r) {
            const int rl = w * 32 + mi * 16 + rg * 4 + r;
            #pragma unroll
            for (int nf = 0; nf < 4; ++nf)
                z2[rl * ZP + nf * 16 + cb] = f2bf(gelu_exact(acc2[mi][nf][r] + prm[128 + nf * 16 + cb]));
        }
    __syncthreads();

    // ---- layer 3: dot(z2[t], W3) + sigmoid, flag borderline
    if (tid < 128) {
        const int t = t0 + tid;
        if (t < kT) {
            float s = 0.f;
            #pragma unroll
            for (int q = 0; q < 8; ++q) {
                short8 zz = *reinterpret_cast<const short8*>(&z2[tid * ZP + q * 8]);
                #pragma unroll
                for (int j = 0; j < 8; ++j)
                    s = fmaf(bf2f((unsigned short)zz[j]), W3[q * 8 + j], s);
            }
            const float p = 1.f / (1.f + expf(-(s + b3[0])));
            out[(size_t)b * kS + t + kW] = p;
            out[(size_t)kB * kS + (size_t)b * kS + t + kW] = (p > 0.5f) ? 1.f : 0.f;
            if (fabsf(p - 0.5f) < 0.02f) {
                int idx = atomicAdd(fcnt, 1);
                flist[idx] = ((unsigned)b << 16) | (unsigned)t;
            }
        }
    }
}

// ================= fp32 cleanup of borderline positions =================
__global__ __launch_bounds__(256, 4)
void fix_kernel(const float* __restrict__ x, const float* __restrict__ Wenc,
                const float* __restrict__ benc, const float* __restrict__ gma,
                const float* __restrict__ bta, const float* __restrict__ W1,
                const float* __restrict__ b1, const float* __restrict__ W2,
                const float* __restrict__ b2, const float* __restrict__ W3,
                const float* __restrict__ b3, const int* __restrict__ fcnt,
                const unsigned int* __restrict__ flist, float* __restrict__ out)
{
    __shared__ float xsh[2][640];
    __shared__ float sh[256];
    __shared__ float z1s[128];
    __shared__ float z2s[64];

    const int tid = threadIdx.x;
    const int n = *fcnt;
    for (int i = blockIdx.x; i < n; i += gridDim.x) {
        const unsigned e = flist[i];
        const int b = e >> 16, t = e & 0xFFFF;
        for (int j = tid; j < 1280; j += 256) {
            int r = j >= 640, k = j - r * 640;
            xsh[r][k] = x[((size_t)b * kS + (t + r * kW + (k >> 5))) * kI + (k & 31)];
        }
        __syncthreads();
        {   // encoder rows for t and t+20: thread = (r, c)
            const int r = tid >> 7, c = tid & 127;
            float h = 0.f;
            for (int k = 0; k < 640; ++k) h = fmaf(xsh[r][k], Wenc[(size_t)k * kH + c], h);
            sh[tid] = h + benc[c];
        }
        __syncthreads();
        {
            const int r = tid >> 7, c = tid & 127;
            float mu = 0.f;
            for (int j = 0; j < 128; ++j) mu += sh[r * 128 + j];
            mu *= (1.f / 128.f);
            float var = 0.f;
            for (int j = 0; j < 128; ++j) { float d = sh[r * 128 + j] - mu; var += d * d; }
            var *= (1.f / 128.f);
            const float ev = gelu_exact((sh[tid] - mu) / sqrtf(var + kEps) * gma[c] + bta[c]);
            __syncthreads();
            sh[tid] = ev;
        }
        __syncthreads();
        if (tid < 128) {   // layer 1
            float z = 0.f;
            for (int k = 0; k < 128; ++k) z = fmaf(sh[k], W1[(size_t)k * kH + tid], z);
            for (int k = 0; k < 128; ++k) z = fmaf(sh[128 + k], W1[(size_t)(128 + k) * kH + tid], z);
            z1s[tid] = gelu_exact(z + b1[tid]);
        }
        __syncthreads();
        if (tid < 64) {    // layer 2
            float z = 0.f;
            for (int k = 0; k < 128; ++k) z = fmaf(z1s[k], W2[(size_t)k * 64 + tid], z);
            z2s[tid] = gelu_exact(z + b2[tid]);
        }
        __syncthreads();
        if (tid == 0) {    // layer 3
            float s = 0.f;
            for (int k = 0; k < 64; ++k) s = fmaf(z2s[k], W3[k], s);
            const float p = 1.f / (1.f + expf(-(s + b3[0])));
            out[(size_t)b * kS + t + kW] = p;
            out[(size_t)kB * kS + (size_t)b * kS + t + kW] = (p > 0.5f) ? 1.f : 0.f;
        }
        __syncthreads();
    }
}

}  // namespace

extern "C" void kernel_launch(void* const* d_in, const int* in_sizes, int n_in,
                              void* d_out, int out_size, void* d_ws, size_t ws_size,
                              hipStream_t stream)
{
    const float* x    = (const float*)d_in[0];
    const float* Wenc = (const float*)d_in[1];
    const float* benc = (const float*)d_in[2];
    const float* gma  = (const float*)d_in[3];
    const float* bta  = (const float*)d_in[4];
    const float* W1   = (const float*)d_in[5];
    const float* b1   = (const float*)d_in[6];
    const float* W2   = (const float*)d_in[7];
    const float* b2   = (const float*)d_in[8];
    const float* W3   = (const float*)d_in[9];
    const float* b3   = (const float*)d_in[10];
    float* out = (float*)d_out;

    char* ws = (char*)d_ws;
    unsigned short* encb  = (unsigned short*)(ws + ENC_OFF);
    unsigned short* xbf   = (unsigned short*)(ws + XBF_OFF);
    unsigned short* WencT = (unsigned short*)(ws + WET_OFF);
    unsigned short* W1T   = (unsigned short*)(ws + W1T_OFF);
    unsigned short* W2T   = (unsigned short*)(ws + W2T_OFF);
    int* fcnt             = (int*)(ws + FC_OFF);
    unsigned int* flist   = (unsigned int*)(ws + FL_OFF);

    hipMemsetAsync(d_out, 0, (size_t)out_size * sizeof(float), stream);
    hipMemsetAsync(fcnt, 0, 16, stream);

    prep_kernel<<<1024, 256, 0, stream>>>(x, Wenc, W1, W2, xbf, WencT, W1T, W2T);
    enc_kernel<<<dim3(16, kB), 256, 0, stream>>>(xbf, WencT, benc, gma, bta, encb);
    cmp_kernel<<<dim3(16, kB), 256, 0, stream>>>(encb, W1T, b1, W2T, b2, W3, b3, out, fcnt, flist);
    fix_kernel<<<1024, 256, 0, stream>>>(x, Wenc, benc, gma, bta, W1, b1, W2, b2, W3, b3,
                                         fcnt, flist, out);
}

// Round 7
// 231.166 us; speedup vs baseline: 3.4742x; 3.4742x over previous
//
#include <hip/hip_runtime.h>
#include <hip/hip_bf16.h>
#include <math.h>

namespace {

constexpr int kB = 32;
constexpr int kS = 2048;
constexpr int kI = 32;
constexpr int kW = 20;
constexpr int kH = 128;
constexpr int kNwin = kS - kW + 1;   // 2029
constexpr int kT = kS - 2 * kW;      // 2008
constexpr float kEps = 1e-5f;
constexpr int FCAP = 16384;          // flag-list capacity

typedef __attribute__((ext_vector_type(8))) short short8;          // 8 bf16 (4 VGPR)
typedef __attribute__((ext_vector_type(8))) unsigned short ush8;   // 16B copy unit
typedef __attribute__((ext_vector_type(4))) float f32x4;

__device__ __forceinline__ unsigned short f2bf(float f) {          // RNE f32->bf16
    unsigned u = __builtin_bit_cast(unsigned, f);
    u += 0x7FFFu + ((u >> 16) & 1u);
    return (unsigned short)(u >> 16);
}
__device__ __forceinline__ float bf2f(unsigned short h) {
    unsigned u = ((unsigned)h) << 16;
    return __builtin_bit_cast(float, u);
}
__device__ __forceinline__ float gelu_exact(float v) {
    return 0.5f * v * (1.0f + erff(v * 0.70710678118654752440f));
}

// ---- workspace layout (bytes) ----
constexpr size_t ENC_OFF = 0;                       // 32*2048*128 bf16 = 16 MB
constexpr size_t XBF_OFF = 16777216;                // 32*2048*32 bf16 = 4 MB
constexpr size_t WET_OFF = XBF_OFF + 4194304;       // WencT [128][640] bf16
constexpr size_t W1T_OFF = WET_OFF + 163840;        // W1T [128][256] bf16
constexpr size_t W2T_OFF = W1T_OFF + 65536;         // W2T [64][128] bf16
constexpr size_t FC_OFF  = W2T_OFF + 16384;         // flag counter (16B)
constexpr size_t FL_OFF  = FC_OFF + 16;             // flag list (FCAP u32)
constexpr size_t HF_OFF  = FL_OFF + 65536;          // hfix [2*FCAP][128] f32 = 16 MB

// ================= prep: bf16 conversions + W transposes =================
__global__ void prep_kernel(const float* __restrict__ x, const float* __restrict__ Wenc,
                            const float* __restrict__ W1, const float* __restrict__ W2,
                            unsigned short* __restrict__ xbf, unsigned short* __restrict__ WencT,
                            unsigned short* __restrict__ W1T, unsigned short* __restrict__ W2T)
{
    const int tid = blockIdx.x * blockDim.x + threadIdx.x;
    const int nth = gridDim.x * blockDim.x;
    for (int i = tid; i < (kB * kS * kI) / 4; i += nth) {
        float4 v = reinterpret_cast<const float4*>(x)[i];
        unsigned short o[4] = {f2bf(v.x), f2bf(v.y), f2bf(v.z), f2bf(v.w)};
        *reinterpret_cast<uint2*>(xbf + i * 4) = *reinterpret_cast<uint2*>(o);
    }
    for (int i = tid; i < kH * 640; i += nth) {     // WencT[n][k] = Wenc[k][n]
        int n = i / 640, k = i - n * 640;
        WencT[i] = f2bf(Wenc[(size_t)k * kH + n]);
    }
    for (int i = tid; i < kH * 256; i += nth) {     // W1T[n][k]
        int n = i >> 8, k = i & 255;
        W1T[i] = f2bf(W1[(size_t)k * kH + n]);
    }
    for (int i = tid; i < 64 * kH; i += nth) {      // W2T[n][k]
        int n = i >> 7, k = i & 127;
        W2T[i] = f2bf(W2[(size_t)k * 64 + n]);
    }
}

// ================= encoder: MFMA GEMM + LN + GELU =================
constexpr int AP = 40;    // LDS pitch in ushorts (80B)

__global__ __launch_bounds__(256, 2)
void enc_kernel(const unsigned short* __restrict__ xbf, const unsigned short* __restrict__ WencT,
                const float* __restrict__ benc, const float* __restrict__ gma,
                const float* __restrict__ bta, unsigned short* __restrict__ encb)
{
    __shared__ unsigned short xs[148 * AP];
    __shared__ unsigned short wt[128 * AP];
    __shared__ float prm[384];

    const int tid = threadIdx.x, b = blockIdx.y, t0 = blockIdx.x * 128;
    const int l = tid & 63, w = tid >> 6;
    const int cb = l & 15, rg = l >> 4;

    if (tid < 128) { prm[tid] = benc[tid]; prm[128 + tid] = gma[tid]; prm[256 + tid] = bta[tid]; }

    for (int i = tid; i < 148 * 4; i += 256) {
        int r = i >> 2, q = i & 3;
        int gr = t0 + r; if (gr > kS - 1) gr = kS - 1;
        ush8 v = *reinterpret_cast<const ush8*>(xbf + ((size_t)(b * kS + gr)) * kI + q * 8);
        *reinterpret_cast<ush8*>(&xs[r * AP + q * 8]) = v;
    }

    f32x4 acc[2][8];
    #pragma unroll
    for (int mi = 0; mi < 2; ++mi)
        #pragma unroll
        for (int nf = 0; nf < 8; ++nf) acc[mi][nf] = f32x4{0.f, 0.f, 0.f, 0.f};

    for (int kc = 0; kc < 20; ++kc) {
        __syncthreads();
        for (int i = tid; i < 128 * 4; i += 256) {
            int n = i >> 2, q = i & 3;
            ush8 v = *reinterpret_cast<const ush8*>(WencT + (size_t)n * 640 + kc * 32 + q * 8);
            *reinterpret_cast<ush8*>(&wt[n * AP + q * 8]) = v;
        }
        __syncthreads();
        short8 a0 = *reinterpret_cast<const short8*>(&xs[(w * 32 + cb + kc) * AP + rg * 8]);
        short8 a1 = *reinterpret_cast<const short8*>(&xs[(w * 32 + 16 + cb + kc) * AP + rg * 8]);
        #pragma unroll
        for (int nf = 0; nf < 8; ++nf) {
            short8 bf = *reinterpret_cast<const short8*>(&wt[(nf * 16 + cb) * AP + rg * 8]);
            acc[0][nf] = __builtin_amdgcn_mfma_f32_16x16x32_bf16(a0, bf, acc[0][nf], 0, 0, 0);
            acc[1][nf] = __builtin_amdgcn_mfma_f32_16x16x32_bf16(a1, bf, acc[1][nf], 0, 0, 0);
        }
    }

    #pragma unroll
    for (int mi = 0; mi < 2; ++mi) {
        #pragma unroll
        for (int r = 0; r < 4; ++r) {
            const int rl = w * 32 + mi * 16 + rg * 4 + r;
            const int t = t0 + rl;
            float h[8];
            float s = 0.f;
            #pragma unroll
            for (int nf = 0; nf < 8; ++nf) { h[nf] = acc[mi][nf][r] + prm[nf * 16 + cb]; s += h[nf]; }
            s += __shfl_xor(s, 1); s += __shfl_xor(s, 2); s += __shfl_xor(s, 4); s += __shfl_xor(s, 8);
            const float mu = s * (1.f / 128.f);
            float s2 = 0.f;
            #pragma unroll
            for (int nf = 0; nf < 8; ++nf) { h[nf] -= mu; s2 += h[nf] * h[nf]; }
            s2 += __shfl_xor(s2, 1); s2 += __shfl_xor(s2, 2); s2 += __shfl_xor(s2, 4); s2 += __shfl_xor(s2, 8);
            const float rstd = 1.f / sqrtf(s2 * (1.f / 128.f) + kEps);
            if (t < kNwin) {
                unsigned short* dst = encb + ((size_t)(b * kS + t)) * kH;
                #pragma unroll
                for (int nf = 0; nf < 8; ++nf) {
                    float v = gelu_exact(h[nf] * rstd * prm[128 + nf * 16 + cb] + prm[256 + nf * 16 + cb]);
                    dst[nf * 16 + cb] = f2bf(v);
                }
            }
        }
    }
}

// ================= comparator: MFMA layers 1-2, vector layer 3 =================
constexpr int EP = 136;
constexpr int ZP = 72;

__global__ __launch_bounds__(256, 2)
void cmp_kernel(const unsigned short* __restrict__ encb, const unsigned short* __restrict__ W1T,
                const float* __restrict__ b1, const unsigned short* __restrict__ W2T,
                const float* __restrict__ b2, const float* __restrict__ W3,
                const float* __restrict__ b3, float* __restrict__ out,
                int* __restrict__ fcnt, unsigned int* __restrict__ flist)
{
    __shared__ unsigned short pool[26624];
    __shared__ unsigned short wt[128 * AP];
    __shared__ float prm[192];

    unsigned short* ebuf = pool;
    unsigned short* z1   = pool;
    unsigned short* z2   = pool + 17408;

    const int tid = threadIdx.x, b = blockIdx.y, t0 = blockIdx.x * 128;
    const int l = tid & 63, w = tid >> 6;
    const int cb = l & 15, rg = l >> 4;

    if (tid < 128) prm[tid] = b1[tid];
    else if (tid < 192) prm[tid] = b2[tid - 128];

    for (int i = tid; i < 148 * 16; i += 256) {
        int r = i >> 4, q = i & 15;
        int gr = t0 + r; if (gr > kNwin - 1) gr = kNwin - 1;
        ush8 v = *reinterpret_cast<const ush8*>(encb + ((size_t)(b * kS + gr)) * kH + q * 8);
        *reinterpret_cast<ush8*>(&ebuf[r * EP + q * 8]) = v;
    }

    f32x4 acc1[2][8];
    #pragma unroll
    for (int mi = 0; mi < 2; ++mi)
        #pragma unroll
        for (int nf = 0; nf < 8; ++nf) acc1[mi][nf] = f32x4{0.f, 0.f, 0.f, 0.f};

    for (int kc = 0; kc < 8; ++kc) {
        __syncthreads();
        for (int i = tid; i < 128 * 4; i += 256) {
            int n = i >> 2, q = i & 3;
            ush8 v = *reinterpret_cast<const ush8*>(W1T + (size_t)n * 256 + kc * 32 + q * 8);
            *reinterpret_cast<ush8*>(&wt[n * AP + q * 8]) = v;
        }
        __syncthreads();
        const int ro = (kc >= 4) ? kW : 0, co = (kc & 3) * 32;
        short8 a0 = *reinterpret_cast<const short8*>(&ebuf[(ro + w * 32 + cb) * EP + co + rg * 8]);
        short8 a1 = *reinterpret_cast<const short8*>(&ebuf[(ro + w * 32 + 16 + cb) * EP + co + rg * 8]);
        #pragma unroll
        for (int nf = 0; nf < 8; ++nf) {
            short8 bf = *reinterpret_cast<const short8*>(&wt[(nf * 16 + cb) * AP + rg * 8]);
            acc1[0][nf] = __builtin_amdgcn_mfma_f32_16x16x32_bf16(a0, bf, acc1[0][nf], 0, 0, 0);
            acc1[1][nf] = __builtin_amdgcn_mfma_f32_16x16x32_bf16(a1, bf, acc1[1][nf], 0, 0, 0);
        }
    }
    __syncthreads();
    #pragma unroll
    for (int mi = 0; mi < 2; ++mi)
        #pragma unroll
        for (int r = 0; r < 4; ++r) {
            const int rl = w * 32 + mi * 16 + rg * 4 + r;
            #pragma unroll
            for (int nf = 0; nf < 8; ++nf)
                z1[rl * EP + nf * 16 + cb] = f2bf(gelu_exact(acc1[mi][nf][r] + prm[nf * 16 + cb]));
        }

    f32x4 acc2[2][4];
    #pragma unroll
    for (int mi = 0; mi < 2; ++mi)
        #pragma unroll
        for (int nf = 0; nf < 4; ++nf) acc2[mi][nf] = f32x4{0.f, 0.f, 0.f, 0.f};

    for (int kc = 0; kc < 4; ++kc) {
        __syncthreads();
        {
            int n = tid >> 2, q = tid & 3;
            if (n < 64) {
                ush8 v = *reinterpret_cast<const ush8*>(W2T + (size_t)n * 128 + kc * 32 + q * 8);
                *reinterpret_cast<ush8*>(&wt[n * AP + q * 8]) = v;
            }
        }
        __syncthreads();
        short8 a0 = *reinterpret_cast<const short8*>(&z1[(w * 32 + cb) * EP + kc * 32 + rg * 8]);
        short8 a1 = *reinterpret_cast<const short8*>(&z1[(w * 32 + 16 + cb) * EP + kc * 32 + rg * 8]);
        #pragma unroll
        for (int nf = 0; nf < 4; ++nf) {
            short8 bf = *reinterpret_cast<const short8*>(&wt[(nf * 16 + cb) * AP + rg * 8]);
            acc2[0][nf] = __builtin_amdgcn_mfma_f32_16x16x32_bf16(a0, bf, acc2[0][nf], 0, 0, 0);
            acc2[1][nf] = __builtin_amdgcn_mfma_f32_16x16x32_bf16(a1, bf, acc2[1][nf], 0, 0, 0);
        }
    }
    __syncthreads();
    #pragma unroll
    for (int mi = 0; mi < 2; ++mi)
        #pragma unroll
        for (int r = 0; r < 4; ++r) {
            const int rl = w * 32 + mi * 16 + rg * 4 + r;
            #pragma unroll
            for (int nf = 0; nf < 4; ++nf)
                z2[rl * ZP + nf * 16 + cb] = f2bf(gelu_exact(acc2[mi][nf][r] + prm[128 + nf * 16 + cb]));
        }
    __syncthreads();

    if (tid < 128) {
        const int t = t0 + tid;
        if (t < kT) {
            float s = 0.f;
            #pragma unroll
            for (int q = 0; q < 8; ++q) {
                short8 zz = *reinterpret_cast<const short8*>(&z2[tid * ZP + q * 8]);
                #pragma unroll
                for (int j = 0; j < 8; ++j)
                    s = fmaf(bf2f((unsigned short)zz[j]), W3[q * 8 + j], s);
            }
            const float p = 1.f / (1.f + expf(-(s + b3[0])));
            out[(size_t)b * kS + t + kW] = p;
            out[(size_t)kB * kS + (size_t)b * kS + t + kW] = (p > 0.5f) ? 1.f : 0.f;
            if (fabsf(p - 0.5f) < 0.01f) {
                int idx = atomicAdd(fcnt, 1);
                if (idx < FCAP) flist[idx] = ((unsigned)b << 16) | (unsigned)t;
            }
        }
    }
}

// ================= fixa: fp32 encoder GEMM for flagged rows =================
// 64 rows x 128 cols per block-iter; Wenc staged in LDS chunks (amortized
// across rows); thread-tile 4x8; writes pre-LN h rows to hfix.
__global__ __launch_bounds__(256, 2)
void fixa_kernel(const float* __restrict__ x, const float* __restrict__ Wenc,
                 const int* __restrict__ fcnt, const unsigned int* __restrict__ flist,
                 float* __restrict__ hfix)
{
    __shared__ float ax[64 * 68];     // A chunk [row][kk], pitch 68 (272B)
    __shared__ float wc[64 * 132];    // W chunk [kk][c], pitch 132 (528B)
    __shared__ int rowbase[64];

    const int tid = threadIdx.x;
    const int ct = tid & 15, rt = tid >> 4;   // 16 col-grps x 8 cols ; 16 row-grps x 4 rows
    int n = *fcnt; if (n > FCAP) n = FCAP;
    const int rows2 = 2 * n;

    for (int base = blockIdx.x * 64; base < rows2; base += gridDim.x * 64) {
        if (tid < 64) {
            int j = base + tid;
            int rb = 0;
            if (j < rows2) {
                unsigned e = flist[j >> 1];
                int bb = (int)(e >> 16), tt = (int)(e & 0xFFFF);
                rb = (bb * kS + tt + (j & 1) * kW) * kI;
            }
            rowbase[tid] = rb;
        }
        float acc[4][8];
        #pragma unroll
        for (int i = 0; i < 4; ++i)
            #pragma unroll
            for (int j2 = 0; j2 < 8; ++j2) acc[i][j2] = 0.f;

        for (int kc = 0; kc < 10; ++kc) {     // K = 640 in chunks of 64
            __syncthreads();
            #pragma unroll
            for (int q = 0; q < 4; ++q) {     // stage A: 64 rows x 16 float4
                int idx = tid + q * 256;
                int row = idx >> 4, kq = idx & 15;
                int gk = kc * 64 + kq * 4;
                const float4 v = *reinterpret_cast<const float4*>(
                    x + rowbase[row] + (gk >> 5) * kI + (gk & 31));
                *reinterpret_cast<float4*>(&ax[row * 68 + kq * 4]) = v;
            }
            #pragma unroll
            for (int q = 0; q < 8; ++q) {     // stage W: 64 kk x 32 float4
                int idx = tid + q * 256;
                int kk = idx >> 5, c4 = idx & 31;
                const float4 v = *reinterpret_cast<const float4*>(
                    Wenc + (size_t)(kc * 64 + kk) * kH + c4 * 4);
                *reinterpret_cast<float4*>(&wc[kk * 132 + c4 * 4]) = v;
            }
            __syncthreads();
            #pragma unroll 4
            for (int kq = 0; kq < 16; ++kq) {
                float4 a4[4];
                #pragma unroll
                for (int i = 0; i < 4; ++i)
                    a4[i] = *reinterpret_cast<const float4*>(&ax[(rt * 4 + i) * 68 + kq * 4]);
                #pragma unroll
                for (int u = 0; u < 4; ++u) {
                    const int kk = kq * 4 + u;
                    const float4 w0 = *reinterpret_cast<const float4*>(&wc[kk * 132 + ct * 8]);
                    const float4 w1 = *reinterpret_cast<const float4*>(&wc[kk * 132 + ct * 8 + 4]);
                    const float wv[8] = {w0.x, w0.y, w0.z, w0.w, w1.x, w1.y, w1.z, w1.w};
                    const float av[4] = {
                        u == 0 ? a4[0].x : (u == 1 ? a4[0].y : (u == 2 ? a4[0].z : a4[0].w)),
                        u == 0 ? a4[1].x : (u == 1 ? a4[1].y : (u == 2 ? a4[1].z : a4[1].w)),
                        u == 0 ? a4[2].x : (u == 1 ? a4[2].y : (u == 2 ? a4[2].z : a4[2].w)),
                        u == 0 ? a4[3].x : (u == 1 ? a4[3].y : (u == 2 ? a4[3].z : a4[3].w))};
                    #pragma unroll
                    for (int i = 0; i < 4; ++i)
                        #pragma unroll
                        for (int j2 = 0; j2 < 8; ++j2)
                            acc[i][j2] = fmaf(av[i], wv[j2], acc[i][j2]);
                }
            }
        }
        #pragma unroll
        for (int i = 0; i < 4; ++i) {
            int j = base + rt * 4 + i;
            if (j < rows2) {
                float* dst = hfix + (size_t)j * kH + ct * 8;
                *reinterpret_cast<float4*>(dst)     = make_float4(acc[i][0], acc[i][1], acc[i][2], acc[i][3]);
                *reinterpret_cast<float4*>(dst + 4) = make_float4(acc[i][4], acc[i][5], acc[i][6], acc[i][7]);
            }
        }
    }
}

// ================= fixb: fp32 LN + MLP for flagged positions =================
__global__ __launch_bounds__(256, 8)
void fixb_kernel(const float* __restrict__ hfix, const unsigned int* __restrict__ flist,
                 const int* __restrict__ fcnt, const float* __restrict__ benc,
                 const float* __restrict__ gma, const float* __restrict__ bta,
                 const float* __restrict__ W1, const float* __restrict__ b1,
                 const float* __restrict__ W2, const float* __restrict__ b2,
                 const float* __restrict__ W3, const float* __restrict__ b3,
                 float* __restrict__ out)
{
    __shared__ float es[256];
    __shared__ float z1s[128];
    __shared__ float z2s[64];
    __shared__ float wred[4];

    const int tid = threadIdx.x;
    const int r = tid >> 7, c = tid & 127;
    int n = *fcnt; if (n > FCAP) n = FCAP;

    for (int i = blockIdx.x; i < n; i += gridDim.x) {
        const unsigned e = flist[i];
        const int b = (int)(e >> 16), t = (int)(e & 0xFFFF);
        const float h = hfix[((size_t)i * 2 + r) * kH + c] + benc[c];
        float s = h;
        #pragma unroll
        for (int m = 1; m < 64; m <<= 1) s += __shfl_xor(s, m, 64);
        if ((tid & 63) == 0) wred[tid >> 6] = s;
        __syncthreads();
        const float mu = (wred[r * 2] + wred[r * 2 + 1]) * (1.f / 128.f);
        const float d = h - mu;
        float s2 = d * d;
        #pragma unroll
        for (int m = 1; m < 64; m <<= 1) s2 += __shfl_xor(s2, m, 64);
        __syncthreads();
        if ((tid & 63) == 0) wred[tid >> 6] = s2;
        __syncthreads();
        const float var = (wred[r * 2] + wred[r * 2 + 1]) * (1.f / 128.f);
        const float rstd = 1.f / sqrtf(var + kEps);
        es[tid] = gelu_exact(d * rstd * gma[c] + bta[c]);
        __syncthreads();
        if (tid < kH) {
            float z = 0.f;
            #pragma unroll 8
            for (int k = 0; k < 256; ++k) z = fmaf(es[k], W1[(size_t)k * kH + tid], z);
            z1s[tid] = gelu_exact(z + b1[tid]);
        }
        __syncthreads();
        if (tid < 64) {
            float z = 0.f;
            #pragma unroll 8
            for (int k = 0; k < kH; ++k) z = fmaf(z1s[k], W2[(size_t)k * 64 + tid], z);
            z2s[tid] = gelu_exact(z + b2[tid]);
        }
        __syncthreads();
        if (tid < 64) {
            float s3 = z2s[tid] * W3[tid];
            #pragma unroll
            for (int m = 1; m < 64; m <<= 1) s3 += __shfl_xor(s3, m, 64);
            if (tid == 0) {
                const float p = 1.f / (1.f + expf(-(s3 + b3[0])));
                out[(size_t)b * kS + t + kW] = p;
                out[(size_t)kB * kS + (size_t)b * kS + t + kW] = (p > 0.5f) ? 1.f : 0.f;
            }
        }
        __syncthreads();
    }
}

}  // namespace

extern "C" void kernel_launch(void* const* d_in, const int* in_sizes, int n_in,
                              void* d_out, int out_size, void* d_ws, size_t ws_size,
                              hipStream_t stream)
{
    const float* x    = (const float*)d_in[0];
    const float* Wenc = (const float*)d_in[1];
    const float* benc = (const float*)d_in[2];
    const float* gma  = (const float*)d_in[3];
    const float* bta  = (const float*)d_in[4];
    const float* W1   = (const float*)d_in[5];
    const float* b1   = (const float*)d_in[6];
    const float* W2   = (const float*)d_in[7];
    const float* b2   = (const float*)d_in[8];
    const float* W3   = (const float*)d_in[9];
    const float* b3   = (const float*)d_in[10];
    float* out = (float*)d_out;

    char* ws = (char*)d_ws;
    unsigned short* encb  = (unsigned short*)(ws + ENC_OFF);
    unsigned short* xbf   = (unsigned short*)(ws + XBF_OFF);
    unsigned short* WencT = (unsigned short*)(ws + WET_OFF);
    unsigned short* W1T   = (unsigned short*)(ws + W1T_OFF);
    unsigned short* W2T   = (unsigned short*)(ws + W2T_OFF);
    int* fcnt             = (int*)(ws + FC_OFF);
    unsigned int* flist   = (unsigned int*)(ws + FL_OFF);
    float* hfix           = (float*)(ws + HF_OFF);

    hipMemsetAsync(d_out, 0, (size_t)out_size * sizeof(float), stream);
    hipMemsetAsync(fcnt, 0, 16, stream);

    prep_kernel<<<1024, 256, 0, stream>>>(x, Wenc, W1, W2, xbf, WencT, W1T, W2T);
    enc_kernel<<<dim3(16, kB), 256, 0, stream>>>(xbf, WencT, benc, gma, bta, encb);
    cmp_kernel<<<dim3(16, kB), 256, 0, stream>>>(encb, W1T, b1, W2T, b2, W3, b3, out, fcnt, flist);
    fixa_kernel<<<512, 256, 0, stream>>>(x, Wenc, fcnt, flist, hfix);
    fixb_kernel<<<2048, 256, 0, stream>>>(hfix, flist, fcnt, benc, gma, bta,
                                          W1, b1, W2, b2, W3, b3, out);
}

// Round 10
// 137.610 us; speedup vs baseline: 5.8362x; 1.6799x over previous
//
#include <hip/hip_runtime.h>
#include <hip/hip_bf16.h>
#include <math.h>

namespace {

constexpr int kB = 32;
constexpr int kS = 2048;
constexpr int kI = 32;
constexpr int kW = 20;
constexpr int kH = 128;
constexpr int kNwin = kS - kW + 1;   // 2029
constexpr int kT = kS - 2 * kW;      // 2008
constexpr float kEps = 1e-5f;
constexpr int FCAP = 4096;           // flag-list capacity
constexpr float kMargin = 1e-3f;     // borderline band half-width

typedef __attribute__((ext_vector_type(8))) short short8;          // 8 bf16 (4 VGPR)
typedef __attribute__((ext_vector_type(8))) unsigned short ush8;   // 16B copy unit
typedef __attribute__((ext_vector_type(4))) float f32x4;

__device__ __forceinline__ unsigned short f2bf(float f) {          // RNE f32->bf16
    unsigned u = __builtin_bit_cast(unsigned, f);
    u += 0x7FFFu + ((u >> 16) & 1u);
    return (unsigned short)(u >> 16);
}
__device__ __forceinline__ float bf2f(unsigned short h) {
    unsigned u = ((unsigned)h) << 16;
    return __builtin_bit_cast(float, u);
}
__device__ __forceinline__ void split2(float v, unsigned short& hi, unsigned short& lo) {
    hi = f2bf(v);
    lo = f2bf(v - bf2f(hi));
}
__device__ __forceinline__ float gelu_exact(float v) {
    return 0.5f * v * (1.0f + erff(v * 0.70710678118654752440f));
}

// ---- workspace layout (bytes) ----
constexpr size_t ENCP_OFF = 0;                        // packed enc (hi|lo<<16) u32: 33.5 MB
constexpr size_t WETH_OFF = 33554432;                 // WencT hi [128][640] bf16
constexpr size_t WETL_OFF = WETH_OFF + 163840;
constexpr size_t W1TH_OFF = WETL_OFF + 163840;        // W1T hi [128][256]
constexpr size_t W1TL_OFF = W1TH_OFF + 65536;
constexpr size_t W2TH_OFF = W1TL_OFF + 65536;         // W2T hi [64][128]
constexpr size_t W2TL_OFF = W2TH_OFF + 16384;
constexpr size_t FC_OFF   = W2TL_OFF + 16384;         // flag counter
constexpr size_t FL_OFF   = FC_OFF + 64;              // flag list (FCAP u32)

// ================= prep: W transposes + hi/lo splits =================
__global__ void prep_kernel(const float* __restrict__ Wenc, const float* __restrict__ W1,
                            const float* __restrict__ W2,
                            unsigned short* __restrict__ WeTh, unsigned short* __restrict__ WeTl,
                            unsigned short* __restrict__ W1Th, unsigned short* __restrict__ W1Tl,
                            unsigned short* __restrict__ W2Th, unsigned short* __restrict__ W2Tl)
{
    const int tid = blockIdx.x * blockDim.x + threadIdx.x;
    const int nth = gridDim.x * blockDim.x;
    for (int i = tid; i < kH * 640; i += nth) {     // WencT[n][k] = Wenc[k][n]
        int n = i / 640, k = i - n * 640;
        split2(Wenc[(size_t)k * kH + n], WeTh[i], WeTl[i]);
    }
    for (int i = tid; i < kH * 256; i += nth) {     // W1T[n][k]
        int n = i >> 8, k = i & 255;
        split2(W1[(size_t)k * kH + n], W1Th[i], W1Tl[i]);
    }
    for (int i = tid; i < 64 * kH; i += nth) {      // W2T[n][k]
        int n = i >> 7, k = i & 127;
        split2(W2[(size_t)k * 64 + n], W2Th[i], W2Tl[i]);
    }
}

// ================= encoder: split-bf16 MFMA GEMM + LN + GELU =================
// Block: 128 t-rows x 128 cols, 256 thr = 4 waves; wave w rows w*32..+31.
constexpr int AP = 40;    // LDS pitch in ushorts (80B)

__global__ __launch_bounds__(256, 2)
void enc_kernel(const float* __restrict__ x,
                const unsigned short* __restrict__ WeTh, const unsigned short* __restrict__ WeTl,
                const float* __restrict__ benc, const float* __restrict__ gma,
                const float* __restrict__ bta, unsigned* __restrict__ encp)
{
    __shared__ unsigned short xsh[148 * AP];
    __shared__ unsigned short xsl[148 * AP];
    __shared__ unsigned short wth[128 * AP];
    __shared__ unsigned short wtl[128 * AP];
    __shared__ float prm[384];

    const int tid = threadIdx.x, b = blockIdx.y, t0 = blockIdx.x * 128;
    const int l = tid & 63, w = tid >> 6;
    const int cb = l & 15, rg = l >> 4;

    if (tid < 128) { prm[tid] = benc[tid]; prm[128 + tid] = gma[tid]; prm[256 + tid] = bta[tid]; }

    // stage x rows t0..t0+147 (f32 -> hi/lo bf16 in-register)
    const float4* x4 = reinterpret_cast<const float4*>(x + (size_t)b * kS * kI);
    for (int i = tid; i < 148 * 8; i += 256) {
        int r = i >> 3, q = i & 7;
        int gr = t0 + r; if (gr > kS - 1) gr = kS - 1;
        float4 v = x4[gr * 8 + q];
        unsigned short h0, h1, h2, h3, l0, l1, l2, l3;
        split2(v.x, h0, l0); split2(v.y, h1, l1); split2(v.z, h2, l2); split2(v.w, h3, l3);
        *reinterpret_cast<uint2*>(&xsh[r * AP + q * 4]) =
            make_uint2((unsigned)h0 | ((unsigned)h1 << 16), (unsigned)h2 | ((unsigned)h3 << 16));
        *reinterpret_cast<uint2*>(&xsl[r * AP + q * 4]) =
            make_uint2((unsigned)l0 | ((unsigned)l1 << 16), (unsigned)l2 | ((unsigned)l3 << 16));
    }

    f32x4 acc[2][8];
    #pragma unroll
    for (int mi = 0; mi < 2; ++mi)
        #pragma unroll
        for (int nf = 0; nf < 8; ++nf) acc[mi][nf] = f32x4{0.f, 0.f, 0.f, 0.f};

    for (int kc = 0; kc < 20; ++kc) {
        __syncthreads();
        #pragma unroll
        for (int u = 0; u < 2; ++u) {         // stage W tile hi/lo (128 n x 32 k)
            int i = tid + 256 * u;
            int n = i >> 2, q = i & 3;
            *reinterpret_cast<ush8*>(&wth[n * AP + q * 8]) =
                *reinterpret_cast<const ush8*>(WeTh + (size_t)n * 640 + kc * 32 + q * 8);
            *reinterpret_cast<ush8*>(&wtl[n * AP + q * 8]) =
                *reinterpret_cast<const ush8*>(WeTl + (size_t)n * 640 + kc * 32 + q * 8);
        }
        __syncthreads();
        const int a0o = (w * 32 + cb + kc) * AP + rg * 8;
        const int a1o = a0o + 16 * AP;
        short8 a0h = *reinterpret_cast<const short8*>(&xsh[a0o]);
        short8 a0l = *reinterpret_cast<const short8*>(&xsl[a0o]);
        short8 a1h = *reinterpret_cast<const short8*>(&xsh[a1o]);
        short8 a1l = *reinterpret_cast<const short8*>(&xsl[a1o]);
        #pragma unroll
        for (int nf = 0; nf < 8; ++nf) {
            const int bo = (nf * 16 + cb) * AP + rg * 8;
            short8 bh = *reinterpret_cast<const short8*>(&wth[bo]);
            short8 bl = *reinterpret_cast<const short8*>(&wtl[bo]);
            acc[0][nf] = __builtin_amdgcn_mfma_f32_16x16x32_bf16(a0h, bh, acc[0][nf], 0, 0, 0);
            acc[0][nf] = __builtin_amdgcn_mfma_f32_16x16x32_bf16(a0l, bh, acc[0][nf], 0, 0, 0);
            acc[0][nf] = __builtin_amdgcn_mfma_f32_16x16x32_bf16(a0h, bl, acc[0][nf], 0, 0, 0);
            acc[1][nf] = __builtin_amdgcn_mfma_f32_16x16x32_bf16(a1h, bh, acc[1][nf], 0, 0, 0);
            acc[1][nf] = __builtin_amdgcn_mfma_f32_16x16x32_bf16(a1l, bh, acc[1][nf], 0, 0, 0);
            acc[1][nf] = __builtin_amdgcn_mfma_f32_16x16x32_bf16(a1h, bl, acc[1][nf], 0, 0, 0);
        }
    }

    // epilogue: C/D col = lane&15, row = (lane>>4)*4 + reg ; LN + GELU ; packed store
    #pragma unroll
    for (int mi = 0; mi < 2; ++mi) {
        #pragma unroll
        for (int r = 0; r < 4; ++r) {
            const int rl = w * 32 + mi * 16 + rg * 4 + r;
            const int t = t0 + rl;
            float h[8];
            float s = 0.f;
            #pragma unroll
            for (int nf = 0; nf < 8; ++nf) { h[nf] = acc[mi][nf][r] + prm[nf * 16 + cb]; s += h[nf]; }
            s += __shfl_xor(s, 1); s += __shfl_xor(s, 2); s += __shfl_xor(s, 4); s += __shfl_xor(s, 8);
            const float mu = s * (1.f / 128.f);
            float s2 = 0.f;
            #pragma unroll
            for (int nf = 0; nf < 8; ++nf) { h[nf] -= mu; s2 += h[nf] * h[nf]; }
            s2 += __shfl_xor(s2, 1); s2 += __shfl_xor(s2, 2); s2 += __shfl_xor(s2, 4); s2 += __shfl_xor(s2, 8);
            const float rstd = 1.f / sqrtf(s2 * (1.f / 128.f) + kEps);
            if (t < kNwin) {
                unsigned* dst = encp + ((size_t)(b * kS + t)) * kH;
                #pragma unroll
                for (int nf = 0; nf < 8; ++nf) {
                    float v = gelu_exact(h[nf] * rstd * prm[128 + nf * 16 + cb] + prm[256 + nf * 16 + cb]);
                    unsigned short hi, lo;
                    split2(v, hi, lo);
                    dst[nf * 16 + cb] = (unsigned)hi | ((unsigned)lo << 16);
                }
            }
        }
    }
}

// ================= comparator: split-bf16 MFMA layers 1-2, f32 layer 3 =================
// Block: 64 t-rows, 256 thr = 4 waves; wave w rows w*16..+15.
__global__ __launch_bounds__(256, 2)
void cmp_kernel(const unsigned* __restrict__ encp,
                const unsigned short* __restrict__ W1Th, const unsigned short* __restrict__ W1Tl,
                const float* __restrict__ b1,
                const unsigned short* __restrict__ W2Th, const unsigned short* __restrict__ W2Tl,
                const float* __restrict__ b2, const float* __restrict__ W3,
                const float* __restrict__ b3, float* __restrict__ out,
                int* __restrict__ fcnt, unsigned* __restrict__ flist)
{
    __shared__ __align__(16) unsigned short pool[27648];   // 55.3 KB, phase-managed
    __shared__ float prm[192];

    unsigned short* esh = pool;              // phase1: 64 x 40
    unsigned short* esl = pool + 2560;       // phase1: 64 x 40
    unsigned short* z1h = pool;              // phase2: 64 x 136
    unsigned short* z1l = pool + 8704;       // phase2: 64 x 136
    unsigned short* wth = pool + 17408;      // 128 x 40 (W1) / 64 x 40 (W2)
    unsigned short* wtl = pool + 22528;
    float* z2f = reinterpret_cast<float*>(pool);   // phase3: 64 x 68 f32

    const int tid = threadIdx.x, b = blockIdx.y, t0 = blockIdx.x * 64;
    const int l = tid & 63, w = tid >> 6;
    const int cb = l & 15, rg = l >> 4;

    if (tid < 128) prm[tid] = b1[tid];
    else if (tid < 192) prm[tid] = b2[tid - 128];

    // ---- layer 1: A[t][k] = enc[t + (k<128?0:20)][k&127], K=256, N=128
    f32x4 acc1[8];
    #pragma unroll
    for (int nf = 0; nf < 8; ++nf) acc1[nf] = f32x4{0.f, 0.f, 0.f, 0.f};

    for (int kc = 0; kc < 8; ++kc) {
        __syncthreads();
        const int ro = (kc < 4) ? 0 : kW, co = (kc & 3) * 32;
        {   // stage enc slice: 64 rows x 32 cols (8 per thread), unpack u32 -> hi/lo
            const int r = tid >> 2, q = tid & 3;
            int gr = t0 + ro + r; if (gr > kNwin - 1) gr = kNwin - 1;
            const unsigned* src = encp + ((size_t)(b * kS + gr)) * kH + co + q * 8;
            const uint4 v0 = *reinterpret_cast<const uint4*>(src);
            const uint4 v1 = *reinterpret_cast<const uint4*>(src + 4);
            *reinterpret_cast<uint2*>(&esh[r * AP + q * 8]) =
                make_uint2((v0.x & 0xFFFFu) | ((v0.y & 0xFFFFu) << 16),
                           (v0.z & 0xFFFFu) | ((v0.w & 0xFFFFu) << 16));
            *reinterpret_cast<uint2*>(&esh[r * AP + q * 8 + 4]) =
                make_uint2((v1.x & 0xFFFFu) | ((v1.y & 0xFFFFu) << 16),
                           (v1.z & 0xFFFFu) | ((v1.w & 0xFFFFu) << 16));
            *reinterpret_cast<uint2*>(&esl[r * AP + q * 8]) =
                make_uint2((v0.x >> 16) | (v0.y & 0xFFFF0000u),
                           (v0.z >> 16) | (v0.w & 0xFFFF0000u));
            *reinterpret_cast<uint2*>(&esl[r * AP + q * 8 + 4]) =
                make_uint2((v1.x >> 16) | (v1.y & 0xFFFF0000u),
                           (v1.z >> 16) | (v1.w & 0xFFFF0000u));
        }
        #pragma unroll
        for (int u = 0; u < 2; ++u) {        // stage W1 tile hi/lo (128 n x 32 k)
            int i = tid + 256 * u;
            int n = i >> 2, q = i & 3;
            *reinterpret_cast<ush8*>(&wth[n * AP + q * 8]) =
                *reinterpret_cast<const ush8*>(W1Th + (size_t)n * 256 + kc * 32 + q * 8);
            *reinterpret_cast<ush8*>(&wtl[n * AP + q * 8]) =
                *reinterpret_cast<const ush8*>(W1Tl + (size_t)n * 256 + kc * 32 + q * 8);
        }
        __syncthreads();
        const int ao = (w * 16 + cb) * AP + rg * 8;
        short8 ah = *reinterpret_cast<const short8*>(&esh[ao]);
        short8 al = *reinterpret_cast<const short8*>(&esl[ao]);
        #pragma unroll
        for (int nf = 0; nf < 8; ++nf) {
            const int bo = (nf * 16 + cb) * AP + rg * 8;
            short8 bh = *reinterpret_cast<const short8*>(&wth[bo]);
            short8 bl = *reinterpret_cast<const short8*>(&wtl[bo]);
            acc1[nf] = __builtin_amdgcn_mfma_f32_16x16x32_bf16(ah, bh, acc1[nf], 0, 0, 0);
            acc1[nf] = __builtin_amdgcn_mfma_f32_16x16x32_bf16(al, bh, acc1[nf], 0, 0, 0);
            acc1[nf] = __builtin_amdgcn_mfma_f32_16x16x32_bf16(ah, bl, acc1[nf], 0, 0, 0);
        }
    }
    __syncthreads();     // es/wt reads done; z1 overlays
    #pragma unroll
    for (int r = 0; r < 4; ++r) {
        const int row = w * 16 + rg * 4 + r;
        #pragma unroll
        for (int nf = 0; nf < 8; ++nf) {
            float v = gelu_exact(acc1[nf][r] + prm[nf * 16 + cb]);
            unsigned short hi, lo;
            split2(v, hi, lo);
            z1h[row * 136 + nf * 16 + cb] = hi;
            z1l[row * 136 + nf * 16 + cb] = lo;
        }
    }

    // ---- layer 2: K=128, N=64
    f32x4 acc2[4];
    #pragma unroll
    for (int nf = 0; nf < 4; ++nf) acc2[nf] = f32x4{0.f, 0.f, 0.f, 0.f};

    for (int kc = 0; kc < 4; ++kc) {
        __syncthreads();
        {   // stage W2 tile hi/lo (64 n x 32 k): 256 units exactly
            int n = tid >> 2, q = tid & 3;
            *reinterpret_cast<ush8*>(&wth[n * AP + q * 8]) =
                *reinterpret_cast<const ush8*>(W2Th + (size_t)n * 128 + kc * 32 + q * 8);
            *reinterpret_cast<ush8*>(&wtl[n * AP + q * 8]) =
                *reinterpret_cast<const ush8*>(W2Tl + (size_t)n * 128 + kc * 32 + q * 8);
        }
        __syncthreads();
        const int ao = (w * 16 + cb) * 136 + kc * 32 + rg * 8;
        short8 ah = *reinterpret_cast<const short8*>(&z1h[ao]);
        short8 al = *reinterpret_cast<const short8*>(&z1l[ao]);
        #pragma unroll
        for (int nf = 0; nf < 4; ++nf) {
            const int bo = (nf * 16 + cb) * AP + rg * 8;
            short8 bh = *reinterpret_cast<const short8*>(&wth[bo]);
            short8 bl = *reinterpret_cast<const short8*>(&wtl[bo]);
            acc2[nf] = __builtin_amdgcn_mfma_f32_16x16x32_bf16(ah, bh, acc2[nf], 0, 0, 0);
            acc2[nf] = __builtin_amdgcn_mfma_f32_16x16x32_bf16(al, bh, acc2[nf], 0, 0, 0);
            acc2[nf] = __builtin_amdgcn_mfma_f32_16x16x32_bf16(ah, bl, acc2[nf], 0, 0, 0);
        }
    }
    __syncthreads();     // z1 reads done; z2f overlays z1h region
    #pragma unroll
    for (int r = 0; r < 4; ++r) {
        const int row = w * 16 + rg * 4 + r;
        #pragma unroll
        for (int nf = 0; nf < 4; ++nf)
            z2f[row * 68 + nf * 16 + cb] = gelu_exact(acc2[nf][r] + prm[128 + nf * 16 + cb]);
    }
    __syncthreads();

    // ---- layer 3: dot(z2[t], W3) + sigmoid; flag borderline
    if (tid < 64) {
        const int t = t0 + tid;
        if (t < kT) {
            float s = 0.f;
            #pragma unroll 8
            for (int k = 0; k < 64; ++k) s = fmaf(z2f[tid * 68 + k], W3[k], s);
            const float p = 1.f / (1.f + expf(-(s + b3[0])));
            out[(size_t)b * kS + t + kW] = p;
            out[(size_t)kB * kS + (size_t)b * kS + t + kW] = (p > 0.5f) ? 1.f : 0.f;
            if (fabsf(p - 0.5f) < kMargin) {
                int idx = atomicAdd(fcnt, 1);
                if (idx < FCAP) flist[idx] = ((unsigned)b << 16) | (unsigned)t;
            }
        }
    }
}

// ================= fix2: full fp32 recompute per flagged position =================
__global__ __launch_bounds__(256, 4)
void fix2_kernel(const float* __restrict__ x, const float* __restrict__ Wenc,
                 const float* __restrict__ benc, const float* __restrict__ gma,
                 const float* __restrict__ bta, const float* __restrict__ W1,
                 const float* __restrict__ b1, const float* __restrict__ W2,
                 const float* __restrict__ b2, const float* __restrict__ W3,
                 const float* __restrict__ b3, const int* __restrict__ fcnt,
                 const unsigned* __restrict__ flist, float* __restrict__ out)
{
    __shared__ float xw[1280];
    __shared__ float es[256];
    __shared__ float z1s[128];
    __shared__ float z2s[64];
    __shared__ float wred[4];

    const int tid = threadIdx.x;
    int n = *fcnt; if (n > FCAP) n = FCAP;

    for (int i = blockIdx.x; i < n; i += gridDim.x) {
        const unsigned e = flist[i];
        const int b = (int)(e >> 16), t = (int)(e & 0xFFFF);
        __syncthreads();
        for (int j = tid; j < 320; j += 256) {      // stage windows t and t+20 (contiguous)
            int r = (j >= 160) ? 1 : 0, u = j - r * 160;
            const float4 v = *reinterpret_cast<const float4*>(
                x + ((size_t)b * kS + t + r * kW) * kI + u * 4);
            *reinterpret_cast<float4*>(&xw[r * 640 + u * 4]) = v;
        }
        __syncthreads();
        const int r = tid >> 7, c = tid & 127;
        float h = 0.f;
        const float* xr = &xw[r * 640];
        #pragma unroll 16
        for (int k = 0; k < 640; ++k) h = fmaf(xr[k], Wenc[(size_t)k * kH + c], h);
        h += benc[c];
        float s = h;
        #pragma unroll
        for (int m = 1; m < 64; m <<= 1) s += __shfl_xor(s, m, 64);
        if ((tid & 63) == 0) wred[tid >> 6] = s;
        __syncthreads();
        const float mu = (wred[r * 2] + wred[r * 2 + 1]) * (1.f / 128.f);
        const float d = h - mu;
        float s2 = d * d;
        #pragma unroll
        for (int m = 1; m < 64; m <<= 1) s2 += __shfl_xor(s2, m, 64);
        __syncthreads();
        if ((tid & 63) == 0) wred[tid >> 6] = s2;
        __syncthreads();
        const float var = (wred[r * 2] + wred[r * 2 + 1]) * (1.f / 128.f);
        es[tid] = gelu_exact(d * (1.f / sqrtf(var + kEps)) * gma[c] + bta[c]);
        __syncthreads();
        if (tid < kH) {
            float z = 0.f;
            #pragma unroll 16
            for (int k = 0; k < 256; ++k) z = fmaf(es[k], W1[(size_t)k * kH + tid], z);
            z1s[tid] = gelu_exact(z + b1[tid]);
        }
        __syncthreads();
        if (tid < 64) {
            float z = 0.f;
            #pragma unroll 16
            for (int k = 0; k < kH; ++k) z = fmaf(z1s[k], W2[(size_t)k * 64 + tid], z);
            z2s[tid] = gelu_exact(z + b2[tid]);
        }
        __syncthreads();
        if (tid < 64) {
            float s3 = z2s[tid] * W3[tid];
            #pragma unroll
            for (int m = 1; m < 64; m <<= 1) s3 += __shfl_xor(s3, m, 64);
            if (tid == 0) {
                const float p = 1.f / (1.f + expf(-(s3 + b3[0])));
                out[(size_t)b * kS + t + kW] = p;
                out[(size_t)kB * kS + (size_t)b * kS + t + kW] = (p > 0.5f) ? 1.f : 0.f;
            }
        }
        __syncthreads();
    }
}

}  // namespace

extern "C" void kernel_launch(void* const* d_in, const int* in_sizes, int n_in,
                              void* d_out, int out_size, void* d_ws, size_t ws_size,
                              hipStream_t stream)
{
    const float* x    = (const float*)d_in[0];
    const float* Wenc = (const float*)d_in[1];
    const float* benc = (const float*)d_in[2];
    const float* gma  = (const float*)d_in[3];
    const float* bta  = (const float*)d_in[4];
    const float* W1   = (const float*)d_in[5];
    const float* b1   = (const float*)d_in[6];
    const float* W2   = (const float*)d_in[7];
    const float* b2   = (const float*)d_in[8];
    const float* W3   = (const float*)d_in[9];
    const float* b3   = (const float*)d_in[10];
    float* out = (float*)d_out;

    char* ws = (char*)d_ws;
    unsigned* encp        = (unsigned*)(ws + ENCP_OFF);
    unsigned short* WeTh  = (unsigned short*)(ws + WETH_OFF);
    unsigned short* WeTl  = (unsigned short*)(ws + WETL_OFF);
    unsigned short* W1Th  = (unsigned short*)(ws + W1TH_OFF);
    unsigned short* W1Tl  = (unsigned short*)(ws + W1TL_OFF);
    unsigned short* W2Th  = (unsigned short*)(ws + W2TH_OFF);
    unsigned short* W2Tl  = (unsigned short*)(ws + W2TL_OFF);
    int* fcnt             = (int*)(ws + FC_OFF);
    unsigned* flist       = (unsigned*)(ws + FL_OFF);

    hipMemsetAsync(d_out, 0, (size_t)out_size * sizeof(float), stream);
    hipMemsetAsync(fcnt, 0, 64, stream);

    prep_kernel<<<256, 256, 0, stream>>>(Wenc, W1, W2, WeTh, WeTl, W1Th, W1Tl, W2Th, W2Tl);
    enc_kernel<<<dim3(16, kB), 256, 0, stream>>>(x, WeTh, WeTl, benc, gma, bta, encp);
    cmp_kernel<<<dim3(32, kB), 256, 0, stream>>>(encp, W1Th, W1Tl, b1, W2Th, W2Tl, b2,
                                                 W3, b3, out, fcnt, flist);
    fix2_kernel<<<4096, 256, 0, stream>>>(x, Wenc, benc, gma, bta, W1, b1, W2, b2, W3, b3,
                                          fcnt, flist, out);
}

// Round 11
// 136.740 us; speedup vs baseline: 5.8733x; 1.0064x over previous
//
#include <hip/hip_runtime.h>
#include <hip/hip_bf16.h>
#include <math.h>

namespace {

constexpr int kB = 32;
constexpr int kS = 2048;
constexpr int kI = 32;
constexpr int kW = 20;
constexpr int kH = 128;
constexpr int kNwin = kS - kW + 1;   // 2029
constexpr int kT = kS - 2 * kW;      // 2008
constexpr float kEps = 1e-5f;
constexpr int FCAP = 4096;
constexpr float kMargin = 1e-3f;

typedef __attribute__((ext_vector_type(8))) short short8;          // 8 bf16
typedef __attribute__((ext_vector_type(8))) unsigned short ush8;   // 16B unit
typedef __attribute__((ext_vector_type(4))) float f32x4;

__device__ __forceinline__ unsigned short f2bf(float f) {
    unsigned u = __builtin_bit_cast(unsigned, f);
    u += 0x7FFFu + ((u >> 16) & 1u);
    return (unsigned short)(u >> 16);
}
__device__ __forceinline__ float bf2f(unsigned short h) {
    unsigned u = ((unsigned)h) << 16;
    return __builtin_bit_cast(float, u);
}
__device__ __forceinline__ void split2(float v, unsigned short& hi, unsigned short& lo) {
    hi = f2bf(v);
    lo = f2bf(v - bf2f(hi));
}
__device__ __forceinline__ float gelu_exact(float v) {
    return 0.5f * v * (1.0f + erff(v * 0.70710678118654752440f));
}
// swizzled ushort index for pitch-32 W tiles: row n, 16B slot q (0..3)
__device__ __forceinline__ int wsw(int n, int q) {
    return n * 32 + ((q ^ ((n >> 1) & 3)) << 3);
}

// ---- workspace layout (bytes) ----
constexpr size_t ENCP_OFF = 0;                        // packed enc u32: 33.5 MB
constexpr size_t WETH_OFF = 33554432;                 // WencT hi [128][640]
constexpr size_t WETL_OFF = WETH_OFF + 163840;
constexpr size_t W1TH_OFF = WETL_OFF + 163840;        // W1T hi [128][256]
constexpr size_t W1TL_OFF = W1TH_OFF + 65536;
constexpr size_t W2TH_OFF = W1TL_OFF + 65536;         // W2T hi [64][128]
constexpr size_t W2TL_OFF = W2TH_OFF + 16384;
constexpr size_t FC_OFF   = W2TL_OFF + 16384;
constexpr size_t FL_OFF   = FC_OFF + 64;

// ================= prep: W transposes + hi/lo splits =================
__global__ void prep_kernel(const float* __restrict__ Wenc, const float* __restrict__ W1,
                            const float* __restrict__ W2,
                            unsigned short* __restrict__ WeTh, unsigned short* __restrict__ WeTl,
                            unsigned short* __restrict__ W1Th, unsigned short* __restrict__ W1Tl,
                            unsigned short* __restrict__ W2Th, unsigned short* __restrict__ W2Tl)
{
    const int tid = blockIdx.x * blockDim.x + threadIdx.x;
    const int nth = gridDim.x * blockDim.x;
    for (int i = tid; i < kH * 640; i += nth) {
        int n = i / 640, k = i - n * 640;
        split2(Wenc[(size_t)k * kH + n], WeTh[i], WeTl[i]);
    }
    for (int i = tid; i < kH * 256; i += nth) {
        int n = i >> 8, k = i & 255;
        split2(W1[(size_t)k * kH + n], W1Th[i], W1Tl[i]);
    }
    for (int i = tid; i < 64 * kH; i += nth) {
        int n = i >> 7, k = i & 127;
        split2(W2[(size_t)k * 64 + n], W2Th[i], W2Tl[i]);
    }
}

// ================= encoder: split-bf16 MFMA + LN + GELU (ping-pong W) =================
// pool layout (ushorts): xsh@0 (147*40) | xsl@5880 | W bufs @11760, stride 8192 (hi), +4096 lo
constexpr int AP = 40;

__global__ __launch_bounds__(256, 2)
void enc_kernel(const float* __restrict__ x,
                const unsigned short* __restrict__ WeTh, const unsigned short* __restrict__ WeTl,
                const float* __restrict__ benc, const float* __restrict__ gma,
                const float* __restrict__ bta, unsigned* __restrict__ encp)
{
    __shared__ __align__(16) unsigned short pool[28144];   // 56.3 KB
    __shared__ float prm[384];

    unsigned short* xsh = pool;
    unsigned short* xsl = pool + 5880;

    const int tid = threadIdx.x, b = blockIdx.y, t0 = blockIdx.x * 128;
    const int l = tid & 63, w = tid >> 6;
    const int cb = l & 15, rg = l >> 4;

    if (tid < 128) { prm[tid] = benc[tid]; prm[128 + tid] = gma[tid]; prm[256 + tid] = bta[tid]; }

    // stage x rows t0..t0+146 (f32 -> hi/lo bf16)
    const float4* x4 = reinterpret_cast<const float4*>(x + (size_t)b * kS * kI);
    for (int i = tid; i < 147 * 8; i += 256) {
        int r = i >> 3, q = i & 7;
        int gr = t0 + r; if (gr > kS - 1) gr = kS - 1;
        float4 v = x4[gr * 8 + q];
        unsigned short h0, h1, h2, h3, l0, l1, l2, l3;
        split2(v.x, h0, l0); split2(v.y, h1, l1); split2(v.z, h2, l2); split2(v.w, h3, l3);
        *reinterpret_cast<uint2*>(&xsh[r * AP + q * 4]) =
            make_uint2((unsigned)h0 | ((unsigned)h1 << 16), (unsigned)h2 | ((unsigned)h3 << 16));
        *reinterpret_cast<uint2*>(&xsl[r * AP + q * 4]) =
            make_uint2((unsigned)l0 | ((unsigned)l1 << 16), (unsigned)l2 | ((unsigned)l3 << 16));
    }

    // W prefetch state: thread covers rows n0 and n0+64, slot q0
    const int n0 = tid >> 2, q0 = tid & 3;
    const int wd0 = wsw(n0, q0), wd1 = wsw(n0 + 64, q0);
    ush8 pwh0, pwl0, pwh1, pwl1;
#define ELOADW(kc) { \
    const unsigned short* sh = WeTh + (size_t)n0 * 640 + (kc) * 32 + q0 * 8; \
    const unsigned short* sl = WeTl + (size_t)n0 * 640 + (kc) * 32 + q0 * 8; \
    pwh0 = *reinterpret_cast<const ush8*>(sh); \
    pwl0 = *reinterpret_cast<const ush8*>(sl); \
    pwh1 = *reinterpret_cast<const ush8*>(sh + 64 * 640); \
    pwl1 = *reinterpret_cast<const ush8*>(sl + 64 * 640); }
#define EWRITEW(buf) { \
    unsigned short* WH = pool + 11760 + (buf) * 8192; \
    unsigned short* WL = WH + 4096; \
    *reinterpret_cast<ush8*>(&WH[wd0]) = pwh0; \
    *reinterpret_cast<ush8*>(&WH[wd1]) = pwh1; \
    *reinterpret_cast<ush8*>(&WL[wd0]) = pwl0; \
    *reinterpret_cast<ush8*>(&WL[wd1]) = pwl1; }

    ELOADW(0); EWRITEW(0);
    __syncthreads();

    f32x4 acc[2][8];
    #pragma unroll
    for (int mi = 0; mi < 2; ++mi)
        #pragma unroll
        for (int nf = 0; nf < 8; ++nf) acc[mi][nf] = f32x4{0.f, 0.f, 0.f, 0.f};

    const int wb_r = cb * 32 + ((rg ^ ((cb >> 1) & 3)) << 3);   // swizzled read base

    for (int kc = 0; kc < 20; ++kc) {
        const int cur = kc & 1;
        if (kc < 19) ELOADW(kc + 1);                 // issue next-chunk loads early
        const unsigned short* WH = pool + 11760 + cur * 8192;
        const unsigned short* WL = WH + 4096;
        const int a0o = (w * 32 + cb + kc) * AP + rg * 8;
        short8 a0h = *reinterpret_cast<const short8*>(&xsh[a0o]);
        short8 a0l = *reinterpret_cast<const short8*>(&xsl[a0o]);
        short8 a1h = *reinterpret_cast<const short8*>(&xsh[a0o + 16 * AP]);
        short8 a1l = *reinterpret_cast<const short8*>(&xsl[a0o + 16 * AP]);
        #pragma unroll
        for (int nf = 0; nf < 8; ++nf) {
            short8 bh = *reinterpret_cast<const short8*>(&WH[nf * 512 + wb_r]);
            short8 bl = *reinterpret_cast<const short8*>(&WL[nf * 512 + wb_r]);
            acc[0][nf] = __builtin_amdgcn_mfma_f32_16x16x32_bf16(a0h, bh, acc[0][nf], 0, 0, 0);
            acc[0][nf] = __builtin_amdgcn_mfma_f32_16x16x32_bf16(a0l, bh, acc[0][nf], 0, 0, 0);
            acc[0][nf] = __builtin_amdgcn_mfma_f32_16x16x32_bf16(a0h, bl, acc[0][nf], 0, 0, 0);
            acc[1][nf] = __builtin_amdgcn_mfma_f32_16x16x32_bf16(a1h, bh, acc[1][nf], 0, 0, 0);
            acc[1][nf] = __builtin_amdgcn_mfma_f32_16x16x32_bf16(a1l, bh, acc[1][nf], 0, 0, 0);
            acc[1][nf] = __builtin_amdgcn_mfma_f32_16x16x32_bf16(a1h, bl, acc[1][nf], 0, 0, 0);
        }
        if (kc < 19) EWRITEW(cur ^ 1);               // write-late into other buffer
        __syncthreads();                             // one barrier per chunk
    }
#undef ELOADW
#undef EWRITEW

    // epilogue: C/D col = lane&15, row = (lane>>4)*4 + reg ; LN + GELU ; packed store
    #pragma unroll
    for (int mi = 0; mi < 2; ++mi) {
        #pragma unroll
        for (int r = 0; r < 4; ++r) {
            const int rl = w * 32 + mi * 16 + rg * 4 + r;
            const int t = t0 + rl;
            float h[8];
            float s = 0.f;
            #pragma unroll
            for (int nf = 0; nf < 8; ++nf) { h[nf] = acc[mi][nf][r] + prm[nf * 16 + cb]; s += h[nf]; }
            s += __shfl_xor(s, 1); s += __shfl_xor(s, 2); s += __shfl_xor(s, 4); s += __shfl_xor(s, 8);
            const float mu = s * (1.f / 128.f);
            float s2 = 0.f;
            #pragma unroll
            for (int nf = 0; nf < 8; ++nf) { h[nf] -= mu; s2 += h[nf] * h[nf]; }
            s2 += __shfl_xor(s2, 1); s2 += __shfl_xor(s2, 2); s2 += __shfl_xor(s2, 4); s2 += __shfl_xor(s2, 8);
            const float rstd = 1.f / sqrtf(s2 * (1.f / 128.f) + kEps);
            if (t < kNwin) {
                unsigned* dst = encp + ((size_t)(b * kS + t)) * kH;
                #pragma unroll
                for (int nf = 0; nf < 8; ++nf) {
                    float v = gelu_exact(h[nf] * rstd * prm[128 + nf * 16 + cb] + prm[256 + nf * 16 + cb]);
                    unsigned short hi, lo;
                    split2(v, hi, lo);
                    dst[nf * 16 + cb] = (unsigned)hi | ((unsigned)lo << 16);
                }
            }
        }
    }
}

// ================= comparator (ping-pong es + W1, ping-pong W2) =================
// pool (ushorts): es bufs @0, stride 5120 (esh), +2560 esl  (2 bufs -> 10240)
//   W1 bufs @10240, stride 8192 (hi), +4096 lo  (ends 26624)
//   phase2: z1h@0 (64*136), z1l@8704 (ends 17408); W2 bufs @17408, stride 4096, +2048 lo (ends 25600)
//   phase3: z2f f32 @0 (64*68)
__global__ __launch_bounds__(256, 2)
void cmp_kernel(const unsigned* __restrict__ encp,
                const unsigned short* __restrict__ W1Th, const unsigned short* __restrict__ W1Tl,
                const float* __restrict__ b1,
                const unsigned short* __restrict__ W2Th, const unsigned short* __restrict__ W2Tl,
                const float* __restrict__ b2, const float* __restrict__ W3,
                const float* __restrict__ b3, float* __restrict__ out,
                int* __restrict__ fcnt, unsigned* __restrict__ flist)
{
    __shared__ __align__(16) unsigned short pool[26624];   // 53.2 KB
    __shared__ float prm[192];

    const int tid = threadIdx.x, b = blockIdx.y, t0 = blockIdx.x * 64;
    const int l = tid & 63, w = tid >> 6;
    const int cb = l & 15, rg = l >> 4;

    if (tid < 128) prm[tid] = b1[tid];
    else if (tid < 192) prm[tid] = b2[tid - 128];

    const int er = tid >> 2, eq = tid & 3;          // es: row 0..63, 8-col group
    const int n0 = tid >> 2, q0 = tid & 3;          // W1: rows n0, n0+64
    const int wd0 = wsw(n0, q0), wd1 = wsw(n0 + 64, q0);
    const int wb_r = cb * 32 + ((rg ^ ((cb >> 1) & 3)) << 3);

    uint4 pe0, pe1;
    ush8 p1h0, p1l0, p1h1, p1l1;
#define CLOADES(kc) { \
    const int ro = ((kc) < 4) ? 0 : kW, co = ((kc) & 3) * 32; \
    int gr = t0 + ro + er; if (gr > kNwin - 1) gr = kNwin - 1; \
    const unsigned* src = encp + ((size_t)(b * kS + gr)) * kH + co + eq * 8; \
    pe0 = *reinterpret_cast<const uint4*>(src); \
    pe1 = *reinterpret_cast<const uint4*>(src + 4); }
#define CWRITEES(buf) { \
    unsigned short* EH = pool + (buf) * 5120; \
    unsigned short* EL = EH + 2560; \
    *reinterpret_cast<uint2*>(&EH[er * AP + eq * 8]) = \
        make_uint2((pe0.x & 0xFFFFu) | ((pe0.y & 0xFFFFu) << 16), \
                   (pe0.z & 0xFFFFu) | ((pe0.w & 0xFFFFu) << 16)); \
    *reinterpret_cast<uint2*>(&EH[er * AP + eq * 8 + 4]) = \
        make_uint2((pe1.x & 0xFFFFu) | ((pe1.y & 0xFFFFu) << 16), \
                   (pe1.z & 0xFFFFu) | ((pe1.w & 0xFFFFu) << 16)); \
    *reinterpret_cast<uint2*>(&EL[er * AP + eq * 8]) = \
        make_uint2((pe0.x >> 16) | (pe0.y & 0xFFFF0000u), \
                   (pe0.z >> 16) | (pe0.w & 0xFFFF0000u)); \
    *reinterpret_cast<uint2*>(&EL[er * AP + eq * 8 + 4]) = \
        make_uint2((pe1.x >> 16) | (pe1.y & 0xFFFF0000u), \
                   (pe1.z >> 16) | (pe1.w & 0xFFFF0000u)); }
#define CLOADW1(kc) { \
    const unsigned short* sh = W1Th + (size_t)n0 * 256 + (kc) * 32 + q0 * 8; \
    const unsigned short* sl = W1Tl + (size_t)n0 * 256 + (kc) * 32 + q0 * 8; \
    p1h0 = *reinterpret_cast<const ush8*>(sh); \
    p1l0 = *reinterpret_cast<const ush8*>(sl); \
    p1h1 = *reinterpret_cast<const ush8*>(sh + 64 * 256); \
    p1l1 = *reinterpret_cast<const ush8*>(sl + 64 * 256); }
#define CWRITEW1(buf) { \
    unsigned short* WH = pool + 10240 + (buf) * 8192; \
    unsigned short* WL = WH + 4096; \
    *reinterpret_cast<ush8*>(&WH[wd0]) = p1h0; \
    *reinterpret_cast<ush8*>(&WH[wd1]) = p1h1; \
    *reinterpret_cast<ush8*>(&WL[wd0]) = p1l0; \
    *reinterpret_cast<ush8*>(&WL[wd1]) = p1l1; }

    CLOADES(0); CLOADW1(0); CWRITEES(0); CWRITEW1(0);
    __syncthreads();

    // ---- layer 1: K=256 in 8 chunks, ping-pong
    f32x4 acc1[8];
    #pragma unroll
    for (int nf = 0; nf < 8; ++nf) acc1[nf] = f32x4{0.f, 0.f, 0.f, 0.f};

    for (int kc = 0; kc < 8; ++kc) {
        const int cur = kc & 1;
        if (kc < 7) { CLOADES(kc + 1); CLOADW1(kc + 1); }
        const unsigned short* EH = pool + cur * 5120;
        const unsigned short* EL = EH + 2560;
        const unsigned short* WH = pool + 10240 + cur * 8192;
        const unsigned short* WL = WH + 4096;
        const int ao = (w * 16 + cb) * AP + rg * 8;
        short8 ah = *reinterpret_cast<const short8*>(&EH[ao]);
        short8 al = *reinterpret_cast<const short8*>(&EL[ao]);
        #pragma unroll
        for (int nf = 0; nf < 8; ++nf) {
            short8 bh = *reinterpret_cast<const short8*>(&WH[nf * 512 + wb_r]);
            short8 bl = *reinterpret_cast<const short8*>(&WL[nf * 512 + wb_r]);
            acc1[nf] = __builtin_amdgcn_mfma_f32_16x16x32_bf16(ah, bh, acc1[nf], 0, 0, 0);
            acc1[nf] = __builtin_amdgcn_mfma_f32_16x16x32_bf16(al, bh, acc1[nf], 0, 0, 0);
            acc1[nf] = __builtin_amdgcn_mfma_f32_16x16x32_bf16(ah, bl, acc1[nf], 0, 0, 0);
        }
        if (kc < 7) { CWRITEES(cur ^ 1); CWRITEW1(cur ^ 1); }
        __syncthreads();
    }
#undef CLOADES
#undef CWRITEES
#undef CLOADW1
#undef CWRITEW1

    // z1 (split) overlays es/W1-buf0 regions; W2 buf0 staged alongside
    unsigned short* z1h = pool;             // 64*136
    unsigned short* z1l = pool + 8704;
    ush8 p2h, p2l;
#define CLOADW2(kc) { \
    p2h = *reinterpret_cast<const ush8*>(W2Th + (size_t)n0 * 128 + (kc) * 32 + q0 * 8); \
    p2l = *reinterpret_cast<const ush8*>(W2Tl + (size_t)n0 * 128 + (kc) * 32 + q0 * 8); }
#define CWRITEW2(buf) { \
    unsigned short* WH = pool + 17408 + (buf) * 4096; \
    unsigned short* WL = WH + 2048; \
    *reinterpret_cast<ush8*>(&WH[wd0]) = p2h; \
    *reinterpret_cast<ush8*>(&WL[wd0]) = p2l; }

    CLOADW2(0);
    #pragma unroll
    for (int r = 0; r < 4; ++r) {
        const int row = w * 16 + rg * 4 + r;
        #pragma unroll
        for (int nf = 0; nf < 8; ++nf) {
            float v = gelu_exact(acc1[nf][r] + prm[nf * 16 + cb]);
            unsigned short hi, lo;
            split2(v, hi, lo);
            z1h[row * 136 + nf * 16 + cb] = hi;
            z1l[row * 136 + nf * 16 + cb] = lo;
        }
    }
    CWRITEW2(0);
    __syncthreads();

    // ---- layer 2: K=128 in 4 chunks, ping-pong W2
    f32x4 acc2[4];
    #pragma unroll
    for (int nf = 0; nf < 4; ++nf) acc2[nf] = f32x4{0.f, 0.f, 0.f, 0.f};

    for (int kc = 0; kc < 4; ++kc) {
        const int cur = kc & 1;
        if (kc < 3) CLOADW2(kc + 1);
        const unsigned short* WH = pool + 17408 + cur * 4096;
        const unsigned short* WL = WH + 2048;
        const int ao = (w * 16 + cb) * 136 + kc * 32 + rg * 8;
        short8 ah = *reinterpret_cast<const short8*>(&z1h[ao]);
        short8 al = *reinterpret_cast<const short8*>(&z1l[ao]);
        #pragma unroll
        for (int nf = 0; nf < 4; ++nf) {
            short8 bh = *reinterpret_cast<const short8*>(&WH[nf * 512 + wb_r]);
            short8 bl = *reinterpret_cast<const short8*>(&WL[nf * 512 + wb_r]);
            acc2[nf] = __builtin_amdgcn_mfma_f32_16x16x32_bf16(ah, bh, acc2[nf], 0, 0, 0);
            acc2[nf] = __builtin_amdgcn_mfma_f32_16x16x32_bf16(al, bh, acc2[nf], 0, 0, 0);
            acc2[nf] = __builtin_amdgcn_mfma_f32_16x16x32_bf16(ah, bl, acc2[nf], 0, 0, 0);
        }
        if (kc < 3) CWRITEW2(cur ^ 1);
        __syncthreads();
    }
#undef CLOADW2
#undef CWRITEW2

    float* z2f = reinterpret_cast<float*>(pool);    // 64*68 f32, overlays z1h (reads done)
    #pragma unroll
    for (int r = 0; r < 4; ++r) {
        const int row = w * 16 + rg * 4 + r;
        #pragma unroll
        for (int nf = 0; nf < 4; ++nf)
            z2f[row * 68 + nf * 16 + cb] = gelu_exact(acc2[nf][r] + prm[128 + nf * 16 + cb]);
    }
    __syncthreads();

    // ---- layer 3: dot + sigmoid; flag borderline
    if (tid < 64) {
        const int t = t0 + tid;
        if (t < kT) {
            float s = 0.f;
            #pragma unroll 8
            for (int k = 0; k < 64; ++k) s = fmaf(z2f[tid * 68 + k], W3[k], s);
            const float p = 1.f / (1.f + expf(-(s + b3[0])));
            out[(size_t)b * kS + t + kW] = p;
            out[(size_t)kB * kS + (size_t)b * kS + t + kW] = (p > 0.5f) ? 1.f : 0.f;
            if (fabsf(p - 0.5f) < kMargin) {
                int idx = atomicAdd(fcnt, 1);
                if (idx < FCAP) flist[idx] = ((unsigned)b << 16) | (unsigned)t;
            }
        }
    }
}

// ================= fix2: full fp32 recompute per flagged position =================
__global__ __launch_bounds__(256, 4)
void fix2_kernel(const float* __restrict__ x, const float* __restrict__ Wenc,
                 const float* __restrict__ benc, const float* __restrict__ gma,
                 const float* __restrict__ bta, const float* __restrict__ W1,
                 const float* __restrict__ b1, const float* __restrict__ W2,
                 const float* __restrict__ b2, const float* __restrict__ W3,
                 const float* __restrict__ b3, const int* __restrict__ fcnt,
                 const unsigned* __restrict__ flist, float* __restrict__ out)
{
    __shared__ float xw[1280];
    __shared__ float es[256];
    __shared__ float z1s[128];
    __shared__ float z2s[64];
    __shared__ float wred[4];

    const int tid = threadIdx.x;
    int n = *fcnt; if (n > FCAP) n = FCAP;

    for (int i = blockIdx.x; i < n; i += gridDim.x) {
        const unsigned e = flist[i];
        const int b = (int)(e >> 16), t = (int)(e & 0xFFFF);
        __syncthreads();
        for (int j = tid; j < 320; j += 256) {
            int r = (j >= 160) ? 1 : 0, u = j - r * 160;
            const float4 v = *reinterpret_cast<const float4*>(
                x + ((size_t)b * kS + t + r * kW) * kI + u * 4);
            *reinterpret_cast<float4*>(&xw[r * 640 + u * 4]) = v;
        }
        __syncthreads();
        const int r = tid >> 7, c = tid & 127;
        float h = 0.f;
        const float* xr = &xw[r * 640];
        #pragma unroll 16
        for (int k = 0; k < 640; ++k) h = fmaf(xr[k], Wenc[(size_t)k * kH + c], h);
        h += benc[c];
        float s = h;
        #pragma unroll
        for (int m = 1; m < 64; m <<= 1) s += __shfl_xor(s, m, 64);
        if ((tid & 63) == 0) wred[tid >> 6] = s;
        __syncthreads();
        const float mu = (wred[r * 2] + wred[r * 2 + 1]) * (1.f / 128.f);
        const float d = h - mu;
        float s2 = d * d;
        #pragma unroll
        for (int m = 1; m < 64; m <<= 1) s2 += __shfl_xor(s2, m, 64);
        __syncthreads();
        if ((tid & 63) == 0) wred[tid >> 6] = s2;
        __syncthreads();
        const float var = (wred[r * 2] + wred[r * 2 + 1]) * (1.f / 128.f);
        es[tid] = gelu_exact(d * (1.f / sqrtf(var + kEps)) * gma[c] + bta[c]);
        __syncthreads();
        if (tid < kH) {
            float z = 0.f;
            #pragma unroll 16
            for (int k = 0; k < 256; ++k) z = fmaf(es[k], W1[(size_t)k * kH + tid], z);
            z1s[tid] = gelu_exact(z + b1[tid]);
        }
        __syncthreads();
        if (tid < 64) {
            float z = 0.f;
            #pragma unroll 16
            for (int k = 0; k < kH; ++k) z = fmaf(z1s[k], W2[(size_t)k * 64 + tid], z);
            z2s[tid] = gelu_exact(z + b2[tid]);
        }
        __syncthreads();
        if (tid < 64) {
            float s3 = z2s[tid] * W3[tid];
            #pragma unroll
            for (int m = 1; m < 64; m <<= 1) s3 += __shfl_xor(s3, m, 64);
            if (tid == 0) {
                const float p = 1.f / (1.f + expf(-(s3 + b3[0])));
                out[(size_t)b * kS + t + kW] = p;
                out[(size_t)kB * kS + (size_t)b * kS + t + kW] = (p > 0.5f) ? 1.f : 0.f;
            }
        }
        __syncthreads();
    }
}

}  // namespace

extern "C" void kernel_launch(void* const* d_in, const int* in_sizes, int n_in,
                              void* d_out, int out_size, void* d_ws, size_t ws_size,
                              hipStream_t stream)
{
    const float* x    = (const float*)d_in[0];
    const float* Wenc = (const float*)d_in[1];
    const float* benc = (const float*)d_in[2];
    const float* gma  = (const float*)d_in[3];
    const float* bta  = (const float*)d_in[4];
    const float* W1   = (const float*)d_in[5];
    const float* b1   = (const float*)d_in[6];
    const float* W2   = (const float*)d_in[7];
    const float* b2   = (const float*)d_in[8];
    const float* W3   = (const float*)d_in[9];
    const float* b3   = (const float*)d_in[10];
    float* out = (float*)d_out;

    char* ws = (char*)d_ws;
    unsigned* encp        = (unsigned*)(ws + ENCP_OFF);
    unsigned short* WeTh  = (unsigned short*)(ws + WETH_OFF);
    unsigned short* WeTl  = (unsigned short*)(ws + WETL_OFF);
    unsigned short* W1Th  = (unsigned short*)(ws + W1TH_OFF);
    unsigned short* W1Tl  = (unsigned short*)(ws + W1TL_OFF);
    unsigned short* W2Th  = (unsigned short*)(ws + W2TH_OFF);
    unsigned short* W2Tl  = (unsigned short*)(ws + W2TL_OFF);
    int* fcnt             = (int*)(ws + FC_OFF);
    unsigned* flist       = (unsigned*)(ws + FL_OFF);

    hipMemsetAsync(d_out, 0, (size_t)out_size * sizeof(float), stream);
    hipMemsetAsync(fcnt, 0, 64, stream);

    prep_kernel<<<256, 256, 0, stream>>>(Wenc, W1, W2, WeTh, WeTl, W1Th, W1Tl, W2Th, W2Tl);
    enc_kernel<<<dim3(16, kB), 256, 0, stream>>>(x, WeTh, WeTl, benc, gma, bta, encp);
    cmp_kernel<<<dim3(32, kB), 256, 0, stream>>>(encp, W1Th, W1Tl, b1, W2Th, W2Tl, b2,
                                                 W3, b3, out, fcnt, flist);
    fix2_kernel<<<4096, 256, 0, stream>>>(x, Wenc, benc, gma, bta, W1, b1, W2, b2, W3, b3,
                                          fcnt, flist, out);
}